// Round 9
// baseline (405.592 us; speedup 1.0000x reference)
//
#include <hip/hip_runtime.h>

typedef _Float16 half8 __attribute__((ext_vector_type(8)));
typedef float f32x4 __attribute__((ext_vector_type(4)));

#define NB 2
#define LS 4800
#define CCH 256
#define W0 80
#define W1 80
#define THRV 0.2f
#define SQS 0.19764235376052370f   // sqrt(1/(C*TEMP)) = sqrt(1/25.6)

#define TBX 38          // col blocks (128 cols each)
#define TBY 75          // row bands (64 rows each)
#define PIMG (TBX * TBY)            // 2850
#define NWG  (PIMG * NB)            // 5700 = 8*712 + 4

// ---- ws float offsets (13.0 MB total; budget ~16.02 MB) ----
#define OF_RST  0                       // float2[NB][LS] row (M, 1/S)
#define OF_CST  19200                   // float2[NB][LS] col (M, 1/S)
#define OF_RWM  38400                   // [NB*LS] conf row max
#define OF_CAND 48000                   // [NB*LS] (int) argmax col
#define OF_CLM  57600                   // [NB*LS] conf col max (atomicMax int)
#define OF_PROW 67200                   // float2 [NB][LS][TBX] row partials (729600 fl)
#define OF_AH   796800                  // _Float16 [NB][LS][CCH]
#define OF_BH   2025600
// pass-1 col partials: float2 [NB][LS][TBY] in OUT[0..2.88M) (conf region, dead until pass 2)

// ---- out float offsets ----
#define O_MASKV 46080000ull
#define O_JIDS  46089600ull
#define O_MKPT  46099200ull
#define O_MCONF 46118400ull

__device__ __forceinline__ void load_lds16(const void* g, void* l) {
    __builtin_amdgcn_global_load_lds((const __attribute__((address_space(1))) void*)g,
                                     (__attribute__((address_space(3))) void*)l, 16, 0, 0);
}

// XCD-aware bijective remap (general m204 form: 5700 = 8*712+4).
__device__ __forceinline__ void swizzle_ids(int& n, int& by, int& bx) {
    const int orig = ((int)blockIdx.z * TBY + (int)blockIdx.y) * TBX + (int)blockIdx.x;
    const int xcd = orig & 7, t = orig >> 3;
    const int wg = (xcd < 4 ? xcd * 713 : 2852 + (xcd - 4) * 712) + t;
    n = wg / PIMG;
    const int rem = wg % PIMG;
    by = rem / TBX; bx = rem % TBX;
}

// --------------------------------------------------------- f32 -> f16 cast --
__global__ __launch_bounds__(256) void conv_half(const float* __restrict__ A,
                                                 const float* __restrict__ B,
                                                 float* __restrict__ ws) {
    const int which = blockIdx.y;
    const float* src = which ? B : A;
    _Float16* dst = (_Float16*)(ws + (which ? OF_BH : OF_AH));
    const int idx = blockIdx.x * 256 + threadIdx.x;   // float4 index, 614400 total
    const float4 v = ((const float4*)src)[idx];
    union { _Float16 h[4]; uint2 u; } p;
    p.h[0] = (_Float16)(v.x * SQS);
    p.h[1] = (_Float16)(v.y * SQS);
    p.h[2] = (_Float16)(v.z * SQS);
    p.h[3] = (_Float16)(v.w * SQS);
    ((uint2*)dst)[idx] = p.u;
}

// ---- A-panel stage: 64 rows x K=256 as 8 slices of [64 rows][4 q-slots]x16B
// slot(row,q) at pos row*4 + (q ^ ((row>>1)&3)) -- the proven conflict-free
// layout; linear LDS dest + pre-swizzled global source (global_load_lds rule).
__device__ __forceinline__ void stage_A(const _Float16* __restrict__ Ah,
                                        _Float16* smA, const int by, const int tid) {
#pragma unroll
    for (int i = 0; i < 4; i++) {
        const int s = i * 512 + tid;          // slot id 0..2047
        const int slice = s >> 8, rem = s & 255, row = rem >> 2, j = rem & 3;
        const int q = j ^ ((row >> 1) & 3);
        load_lds16(Ah + (size_t)(by * 64 + row) * CCH + slice * 32 + q * 8, smA + s * 8);
    }
}

// ---- barrier-free K-loop: per-wave 32x32 tile, A from LDS, B direct from L2
// into registers with depth-2 prefetch (compiler emits counted vmcnt; no
// LDS buffers to recycle -> NO barriers). kt indices compile-time via unroll.
__device__ __forceinline__ void kloop(const _Float16* smA,
                                      const _Float16* __restrict__ Bh,
                                      const int colb, const int wrow,
                                      const int m, const int quad,
                                      f32x4 (&acc)[2][2]) {
    const _Float16* bp0 = Bh + (size_t)(colb + m) * CCH + quad * 8;
    const _Float16* bp1 = bp0 + 16 * CCH;
    half8 Bs[3][2], Af[2][2];
    Bs[0][0] = *(const half8*)bp0;
    Bs[0][1] = *(const half8*)bp1;
    Bs[1][0] = *(const half8*)(bp0 + 32);
    Bs[1][1] = *(const half8*)(bp1 + 32);
#pragma unroll
    for (int a = 0; a < 2; a++) {
        const int rl = wrow * 32 + a * 16 + m;
        const int sl = rl * 4 + (quad ^ ((rl >> 1) & 3));
        Af[0][a] = *(const half8*)&smA[sl * 8];
    }
#pragma unroll
    for (int kt = 0; kt < 8; kt++) {
        if (kt < 6) {                          // B prefetch depth 2
            Bs[(kt + 2) % 3][0] = *(const half8*)(bp0 + (kt + 2) * 32);
            Bs[(kt + 2) % 3][1] = *(const half8*)(bp1 + (kt + 2) * 32);
        }
        if (kt < 7) {                          // A prefetch depth 1
#pragma unroll
            for (int a = 0; a < 2; a++) {
                const int rl = wrow * 32 + a * 16 + m;
                const int sl = (kt + 1) * 256 + rl * 4 + (quad ^ ((rl >> 1) & 3));
                Af[(kt + 1) & 1][a] = *(const half8*)&smA[sl * 8];
            }
        }
#pragma unroll
        for (int a = 0; a < 2; a++)
#pragma unroll
            for (int b = 0; b < 2; b++)
                acc[a][b] = __builtin_amdgcn_mfma_f32_16x16x32_f16(Af[kt & 1][a], Bs[kt % 3][b], acc[a][b], 0, 0, 0);
    }
}

// ------------------------- pass 1: stats-only GEMM --------------------------
__global__ __launch_bounds__(512, 4) void gemm_stats(float* __restrict__ out,
                                                     float* __restrict__ ws) {
    __shared__ __align__(16) _Float16 smA[16384];   // 32KB
    __shared__ float rs[64][4][2];                  // (T, sum) per row per wcol
    __shared__ float cs[128][2][2];                 // (T, sum) per col per wrow
    int n, by, bx;
    swizzle_ids(n, by, bx);
    const _Float16* Ah = (const _Float16*)(ws + OF_AH) + (size_t)n * LS * CCH;
    const _Float16* Bh = (const _Float16*)(ws + OF_BH) + (size_t)n * LS * CCH;
    const int tid = threadIdx.x;
    const int lane = tid & 63, w = tid >> 6;
    const int wrow = w >> 2, wcol = w & 3;
    const int m = lane & 15, quad = lane >> 4;

    stage_A(Ah, smA, by, tid);
    __syncthreads();                                // barrier #1 (only K-side barrier)

    const int colb = bx * 128 + wcol * 32;
    const bool bvalid = colb < LS;                  // tiles fully valid or fully OOB
    f32x4 acc[2][2];
    {
        f32x4 z = {0.f, 0.f, 0.f, 0.f};
        acc[0][0] = z; acc[0][1] = z; acc[1][0] = z; acc[1][1] = z;
    }
    if (bvalid) {
        kloop(smA, Bh, colb, wrow, m, quad, acc);

        // wave-uniform reference max (valid online-softmax partial)
        float T = -1e30f;
#pragma unroll
        for (int a = 0; a < 2; a++)
#pragma unroll
            for (int b = 0; b < 2; b++)
#pragma unroll
                for (int reg = 0; reg < 4; reg++) T = fmaxf(T, acc[a][b][reg]);
#pragma unroll
        for (int d = 1; d < 64; d <<= 1) T = fmaxf(T, __shfl_xor(T, d, 64));

#pragma unroll
        for (int a = 0; a < 2; a++)
#pragma unroll
            for (int b = 0; b < 2; b++)
#pragma unroll
                for (int reg = 0; reg < 4; reg++)
                    acc[a][b][reg] = __expf(acc[a][b][reg] - T);

        // row sums: per (a,reg) sum over b then 16 m-lanes
#pragma unroll
        for (int a = 0; a < 2; a++)
#pragma unroll
            for (int reg = 0; reg < 4; reg++) {
                float s = acc[a][0][reg] + acc[a][1][reg];
#pragma unroll
                for (int d = 1; d < 16; d <<= 1) s += __shfl_xor(s, d, 64);
                if (m == 0) {
                    const int rl = wrow * 32 + a * 16 + quad * 4 + reg;
                    rs[rl][wcol][0] = T; rs[rl][wcol][1] = s;
                }
            }
        // col sums: per b sum over (a,reg) then quads
#pragma unroll
        for (int b = 0; b < 2; b++) {
            float s = 0.f;
#pragma unroll
            for (int a = 0; a < 2; a++)
#pragma unroll
                for (int reg = 0; reg < 4; reg++) s += acc[a][b][reg];
            s += __shfl_xor(s, 16, 64);
            s += __shfl_xor(s, 32, 64);
            if (quad == 0) {
                const int cl = wcol * 32 + b * 16 + m;
                cs[cl][wrow][0] = T; cs[cl][wrow][1] = s;
            }
        }
    } else {
        if (m == 0) {
#pragma unroll
            for (int a = 0; a < 2; a++)
#pragma unroll
                for (int reg = 0; reg < 4; reg++) {
                    const int rl = wrow * 32 + a * 16 + quad * 4 + reg;
                    rs[rl][wcol][0] = -1e30f; rs[rl][wcol][1] = 0.f;
                }
        }
        if (quad == 0) {
#pragma unroll
            for (int b = 0; b < 2; b++) {
                const int cl = wcol * 32 + b * 16 + m;
                cs[cl][wrow][0] = -1e30f; cs[cl][wrow][1] = 0.f;
            }
        }
    }
    __syncthreads();                                // barrier #2
    if (tid < 64) {
        float M = -1e30f, S = 0.f;
#pragma unroll
        for (int k = 0; k < 4; k++) {
            const float mk = rs[tid][k][0], sk = rs[tid][k][1];
            const float nm = fmaxf(M, mk);
            S = S * __expf(M - nm) + sk * __expf(mk - nm);
            M = nm;
        }
        ((float2*)(ws + OF_PROW))[((size_t)n * LS + by * 64 + tid) * TBX + bx] = make_float2(M, S);
    } else if (tid < 192) {
        const int c = tid - 64;
        const int col = bx * 128 + c;
        if (col < LS) {
            float M = cs[c][0][0], S = cs[c][0][1];
            const float mk = cs[c][1][0], sk = cs[c][1][1];
            const float nm = fmaxf(M, mk);
            S = S * __expf(M - nm) + sk * __expf(mk - nm);
            M = nm;
            ((float2*)out)[((size_t)n * LS + col) * TBY + by] = make_float2(M, S);
        }
    }
}

// -------------------------------------------------- combine partials --------
__global__ __launch_bounds__(256) void combine_stats(const float* __restrict__ out,
                                                     float* __restrict__ ws) {
    const int idx = blockIdx.x * 256 + threadIdx.x;   // 19200 total
    const int half_ = idx >= 9600;
    const int i = idx - half_ * 9600;
    const int n = i / LS, r = i % LS;
    float M = -1e30f, S = 0.f;
    if (!half_) {
        const float2* P = (const float2*)(ws + OF_PROW) + ((size_t)n * LS + r) * TBX;
        for (int b = 0; b < TBX; b++) {
            const float2 p = P[b];
            const float nm = fmaxf(M, p.x);
            S = S * __expf(M - nm) + p.y * __expf(p.x - nm);
            M = nm;
        }
        ((float2*)(ws + OF_RST))[n * LS + r] = make_float2(M, 1.0f / S);
    } else {
        const float2* P = (const float2*)out + ((size_t)n * LS + r) * TBY;
        for (int b = 0; b < TBY; b++) {
            const float2 p = P[b];
            const float nm = fmaxf(M, p.x);
            S = S * __expf(M - nm) + p.y * __expf(p.x - nm);
            M = nm;
        }
        ((float2*)(ws + OF_CST))[n * LS + r] = make_float2(M, 1.0f / S);
        ws[OF_CLM + i] = 0.0f;   // init for pass-2 block-level atomicMax
    }
}

// ---- pass 2: recompute GEMM, write conf, fused row-argmax + colmax atomics -
__global__ __launch_bounds__(512, 4) void gemm_conf(float* __restrict__ out,
                                                    float* __restrict__ ws) {
    __shared__ __align__(16) _Float16 smA[16384];   // 32KB
    __shared__ float rsv[64][4][2];                 // (bestv, idx-bits)
    __shared__ float csv[128][2];                   // colmax per wrow
    int n, by, bx;
    swizzle_ids(n, by, bx);
    const _Float16* Ah = (const _Float16*)(ws + OF_AH) + (size_t)n * LS * CCH;
    const _Float16* Bh = (const _Float16*)(ws + OF_BH) + (size_t)n * LS * CCH;
    const int tid = threadIdx.x;
    const int lane = tid & 63, w = tid >> 6;
    const int wrow = w >> 2, wcol = w & 3;
    const int m = lane & 15, quad = lane >> 4;

    stage_A(Ah, smA, by, tid);
    __syncthreads();                                // barrier #1

    const int colb = bx * 128 + wcol * 32;
    const bool bvalid = colb < LS;
    f32x4 acc[2][2];
    {
        f32x4 z = {0.f, 0.f, 0.f, 0.f};
        acc[0][0] = z; acc[0][1] = z; acc[1][0] = z; acc[1][1] = z;
    }
    if (bvalid) {
        kloop(smA, Bh, colb, wrow, m, quad, acc);

        float* On = out + (size_t)n * LS * LS;
        float colm[2] = {-1.f, -1.f};
        float cmx[2], csi[2];
#pragma unroll
        for (int b = 0; b < 2; b++) {
            const float2 cv = ((const float2*)(ws + OF_CST))[n * LS + colb + b * 16 + m];
            cmx[b] = cv.x; csi[b] = cv.y;
        }
#pragma unroll
        for (int a = 0; a < 2; a++) {
#pragma unroll
            for (int reg = 0; reg < 4; reg++) {
                const int rl = wrow * 32 + a * 16 + quad * 4 + reg;
                const int gr = by * 64 + rl;
                const float2 rv = ((const float2*)(ws + OF_RST))[n * LS + gr];
                float bestv = -1.f; int besti = 0;
#pragma unroll
                for (int b = 0; b < 2; b++) {
                    const float c = __expf(2.f * acc[a][b][reg] - rv.x - cmx[b]) * (rv.y * csi[b]);
                    On[(size_t)gr * LS + colb + b * 16 + m] = c;
                    if (c > bestv) { bestv = c; besti = colb + b * 16 + m; }  // b ascends col
                    colm[b] = fmaxf(colm[b], c);
                }
#pragma unroll
                for (int d = 1; d < 16; d <<= 1) {
                    const float ov = __shfl_xor(bestv, d, 64);
                    const int oi = __shfl_xor(besti, d, 64);
                    if (ov > bestv || (ov == bestv && oi < besti)) { bestv = ov; besti = oi; }
                }
                if (m == 0) {
                    rsv[rl][wcol][0] = bestv;
                    rsv[rl][wcol][1] = __int_as_float(besti);
                }
            }
        }
#pragma unroll
        for (int b = 0; b < 2; b++) {
            float v = colm[b];
            v = fmaxf(v, __shfl_xor(v, 16, 64));
            v = fmaxf(v, __shfl_xor(v, 32, 64));
            if (quad == 0) csv[wcol * 32 + b * 16 + m][wrow] = v;
        }
    } else {
        if (m == 0) {
#pragma unroll
            for (int a = 0; a < 2; a++)
#pragma unroll
                for (int reg = 0; reg < 4; reg++) {
                    const int rl = wrow * 32 + a * 16 + quad * 4 + reg;
                    rsv[rl][wcol][0] = -1.f; rsv[rl][wcol][1] = 0.f;
                }
        }
        if (quad == 0) {
#pragma unroll
            for (int b = 0; b < 2; b++) csv[wcol * 32 + b * 16 + m][wrow] = -1.f;
        }
    }
    __syncthreads();                                // barrier #2
    if (tid < 64) {
        float bv = -2.f; int bi = 0;
#pragma unroll
        for (int k = 0; k < 4; k++) {               // wcol ascending = col ascending
            const float v = rsv[tid][k][0]; const int ii = __float_as_int(rsv[tid][k][1]);
            if (v > bv || (v == bv && ii < bi)) { bv = v; bi = ii; }
        }
        ((float2*)(ws + OF_PROW))[((size_t)n * LS + by * 64 + tid) * TBX + bx] =
            make_float2(bv, __int_as_float(bi));
    } else if (tid < 192) {
        const int c = tid - 64;
        const int col = bx * 128 + c;
        if (col < LS) {
            const float v = fmaxf(csv[c][0], csv[c][1]);
            if (v > 0.f)
                atomicMax((int*)(ws + OF_CLM) + n * LS + col, __float_as_int(v));
        }
    }
}

// ------------------------------------------- combine row argmax partials ----
__global__ __launch_bounds__(256) void combine_max(float* __restrict__ ws) {
    const int i = blockIdx.x * 256 + threadIdx.x;   // 9600 total
    if (i >= NB * LS) return;
    const int n = i / LS, r = i % LS;
    const float2* P = (const float2*)(ws + OF_PROW) + ((size_t)n * LS + r) * TBX;
    float bv = -2.f; int bi = 0;
    for (int b = 0; b < TBX; b++) {
        const float2 p = P[b];
        const int pi = __float_as_int(p.y);
        if (p.x > bv || (p.x == bv && pi < bi)) { bv = p.x; bi = pi; }
    }
    ws[OF_RWM + i] = bv;
    ((int*)ws)[OF_CAND + i] = bi;
}

// ------------------------------------------------------------- matching -----
__global__ __launch_bounds__(256) void match_pass(const float* __restrict__ ws,
                                                  float* __restrict__ out) {
    const int idx = blockIdx.x * 256 + threadIdx.x;
    if (idx >= NB * LS) return;
    const int n = idx / LS, l = idx % LS;
    const float rwm = ws[OF_RWM + idx];
    const int cand = ((const int*)ws)[OF_CAND + idx];
    const float clm = ws[OF_CLM + n * LS + cand];
    const int y0 = l / W0, x0 = l % W0;
    const int y1 = cand / W1, x1 = cand % W1;
    const bool b0 = (y0 >= 2 && y0 < 58 && x0 >= 2 && x0 < 78);
    const bool b1 = (y1 >= 2 && y1 < 58 && x1 >= 2 && x1 < 78);
    const bool matched = (rwm > THRV) && b0 && b1 && (rwm == clm);
    const int j = matched ? cand : 0;
    out[O_MASKV + idx] = matched ? 1.f : 0.f;
    out[O_JIDS + idx] = (float)j;
    out[O_MKPT + (size_t)idx * 2 + 0] = (float)(j % W1);
    out[O_MKPT + (size_t)idx * 2 + 1] = (float)(j / W1);
    out[O_MCONF + idx] = matched ? rwm : 0.f;
}

// -------------------------------------------------------------- launch ------
extern "C" void kernel_launch(void* const* d_in, const int* in_sizes, int n_in,
                              void* d_out, int out_size, void* d_ws, size_t ws_size,
                              hipStream_t stream) {
    const float* f0 = (const float*)d_in[0];
    const float* f1 = (const float*)d_in[1];
    float* out = (float*)d_out;
    float* ws = (float*)d_ws;

    conv_half<<<dim3(2400, 2), 256, 0, stream>>>(f0, f1, ws);
    gemm_stats<<<dim3(TBX, TBY, NB), 512, 0, stream>>>(out, ws);
    combine_stats<<<75, 256, 0, stream>>>(out, ws);
    gemm_conf<<<dim3(TBX, TBY, NB), 512, 0, stream>>>(out, ws);
    combine_max<<<38, 256, 0, stream>>>(ws);
    match_pass<<<38, 256, 0, stream>>>(ws, out);
}